// Round 3
// baseline (105.841 us; speedup 1.0000x reference)
//
#include <hip/hip_runtime.h>

#define KOBJ 256
#define NCOPY 32
#define EPSF 1e-6f
#define QMIN 0.5f

struct WS {
    float4 adata[KOBJ];                    // 4KB, 16B-aligned: x_alpha, y_alpha, q_alpha (0 if empty), beta_alpha
    unsigned long long key[NCOPY][KOBJ];   // 64KB privatized argmax keys
    double pay[KOBJ][NCOPY][5];            // 320KB privatized payload sums: pw + 4 components
    double acc[8];                         // 0:att 1:rep 2:noise_beta 3:noise_cnt 4:minb 5:nobj
};

__device__ inline float clipb(float b) {
    return fminf(fmaxf(b, 1e-4f), 1.0f - 1e-4f);
}

__device__ inline float wave_sum(float v) {
    #pragma unroll
    for (int o = 32; o > 0; o >>= 1) v += __shfl_down(v, o, 64);
    return v;
}

__device__ inline double wave_sum_d(double v) {
    #pragma unroll
    for (int o = 32; o > 0; o >>= 1) v += __shfl_down(v, o, 64);
    return v;
}

// ---------------- pass 1: per-object argmax of beta (privatized) + noise sums ----------------
__global__ __launch_bounds__(256) void k_pass1(const float* __restrict__ beta_in,
                                               const int* __restrict__ tidx,
                                               int n, WS* __restrict__ ws) {
    int i = blockIdx.x * 256 + threadIdx.x;
    int c = blockIdx.x & (NCOPY - 1);
    float nb = 0.f, ncnt = 0.f;
    if (i < n) {
        float b = clipb(beta_in[i]);
        int t = tidx[i];
        if (t >= 0) {
            unsigned int bits = __float_as_uint(b);  // b>0 -> bits monotone in b
            unsigned long long kv =
                ((unsigned long long)bits << 32) | (unsigned long long)(0xFFFFFFFFu - (unsigned int)i);
            atomicMax(&ws->key[c][t], kv);
        } else {
            nb = b; ncnt = 1.f;   // noise point
        }
    }
    __shared__ float s0[4], s1[4];
    float a = wave_sum(nb), cc = wave_sum(ncnt);
    int lane = threadIdx.x & 63, w = threadIdx.x >> 6;
    if (lane == 0) { s0[w] = a; s1[w] = cc; }
    __syncthreads();
    if (threadIdx.x == 0) {
        float A = s0[0] + s0[1] + s0[2] + s0[3];
        float C = s1[0] + s1[1] + s1[2] + s1[3];
        if (C != 0.f) {
            atomicAdd(&ws->acc[2], (double)A);
            atomicAdd(&ws->acc[3], (double)C);
        }
    }
}

// ---------------- pass 2: merge keys, gather alpha data per object ----------------
__global__ __launch_bounds__(256) void k_gather(const float* __restrict__ beta_in,
                                                const float2* __restrict__ ccoords,
                                                WS* __restrict__ ws) {
    int k = threadIdx.x;
    unsigned long long kv = 0ull;
    #pragma unroll 8
    for (int c = 0; c < NCOPY; ++c) {
        unsigned long long v = ws->key[c][k];
        kv = v > kv ? v : kv;
    }
    float minb = 0.f, nobj = 0.f;
    if (kv != 0ull) {
        unsigned int idx = 0xFFFFFFFFu - (unsigned int)(kv & 0xFFFFFFFFull);
        float b = clipb(beta_in[idx]);
        float at = atanhf(b);
        float qa = at * at + QMIN;
        float2 xy = ccoords[idx];
        ws->adata[k] = make_float4(xy.x, xy.y, qa, b);
        minb = 1.f - b; nobj = 1.f;
    } else {
        ws->adata[k] = make_float4(0.f, 0.f, 0.f, 0.f);
    }
    __shared__ float s0[4], s1[4];
    float a = wave_sum(minb), c = wave_sum(nobj);
    int lane = threadIdx.x & 63, w = threadIdx.x >> 6;
    if (lane == 0) { s0[w] = a; s1[w] = c; }
    __syncthreads();
    if (threadIdx.x == 0) {
        ws->acc[4] = (double)(s0[0] + s0[1] + s0[2] + s0[3]);
        ws->acc[5] = (double)(s1[0] + s1[1] + s1[2] + s1[3]);
    }
}

// repulsion term for one alpha entry (a.* live in SGPRs when load is scalar)
__device__ inline float repterm(float4 a, float cx, float cy) {
    float dx = cx - a.x, dy = cy - a.y;
    float d2e = fmaf(dx, dx, fmaf(dy, dy, EPSF));
    float s = __builtin_amdgcn_sqrtf(d2e);
    return a.z * fmaxf(1.f - s, 0.f);
}

// ---------------- pass 3: main N x K pass (alpha data via wave-uniform scalar loads) ----------------
__global__ __launch_bounds__(256) void k_main(const float* __restrict__ beta_in,
                                              const float2* __restrict__ ccoords,
                                              const float* __restrict__ energy,
                                              const float2* __restrict__ pos,
                                              const float* __restrict__ ptime,
                                              const float* __restrict__ pid,
                                              const int* __restrict__ tidx,
                                              const float* __restrict__ tenergy,
                                              const float2* __restrict__ tpos,
                                              const float* __restrict__ ttime,
                                              int n, WS* __restrict__ ws) {
    int i = blockIdx.x * 256 + threadIdx.x;
    int c = blockIdx.x & (NCOPY - 1);
    bool valid = i < n;
    int ii = valid ? i : (n - 1);

    const float4* __restrict__ ad = ws->adata;   // wave-uniform indexing -> s_load

    float b = clipb(beta_in[ii]);
    float at = atanhf(b);
    float q = at * at + QMIN;
    float2 xy = ccoords[ii];
    float cx = xy.x, cy = xy.y;
    int t = valid ? tidx[ii] : -1;

    // K-loop: unconditional, uniform loads, 4 independent accumulator chains
    float r0 = 0.f, r1 = 0.f, r2 = 0.f, r3 = 0.f;
    for (int kk = 0; kk < KOBJ; kk += 8) {
        float4 a0 = ad[kk + 0]; float4 a1 = ad[kk + 1];
        float4 a2 = ad[kk + 2]; float4 a3 = ad[kk + 3];
        float4 a4 = ad[kk + 4]; float4 a5 = ad[kk + 5];
        float4 a6 = ad[kk + 6]; float4 a7 = ad[kk + 7];
        r0 += repterm(a0, cx, cy);
        r1 += repterm(a1, cx, cy);
        r2 += repterm(a2, cx, cy);
        r3 += repterm(a3, cx, cy);
        r0 += repterm(a4, cx, cy);
        r1 += repterm(a5, cx, cy);
        r2 += repterm(a6, cx, cy);
        r3 += repterm(a7, cx, cy);
    }
    float repn = (r0 + r1) + (r2 + r3);

    float att = 0.f;
    if (t >= 0) {
        float4 a = ad[t];                       // divergent index -> vector load, rare path data
        float dx = cx - a.x, dy = cy - a.y;
        float d2 = fmaf(dx, dx, dy * dy);       // att uses d2 WITHOUT eps
        repn -= repterm(a, cx, cy);             // exclude own k from repulsion
        att = q * a.z * d2;

        if (b > 0.1f * a.w) {                   // payload weight condition
            float te = tenergy[ii];
            float ste = __builtin_amdgcn_sqrtf(te + 0.001f);
            float l = fabsf(te - energy[ii]) / (ste + 1.0f);
            float d = ste * 2.0f;
            float el = (l < d) ? l * l : fmaf(2.f * d, l - d, d * d);
            float2 pp = pos[ii], tp = tpos[ii];
            float px = pp.x - tp.x, py = pp.y - tp.y;
            float pl = fmaf(px, px, py * py) * 0.01f;
            float td = ttime[ii] * 1e9f - ptime[ii];
            float tl = td * td;
            float s = 0.f;
            #pragma unroll
            for (int cc = 0; cc < 6; ++cc) { float v = pid[6 * ii + cc]; s = fmaf(v, v, s); }
            float cl = 1e-8f * (s * (1.f / 6.f));
            double* p = ws->pay[t][c];
            atomicAdd(p + 0, (double)b);
            atomicAdd(p + 1, (double)(b * el));
            atomicAdd(p + 2, (double)(b * pl));
            atomicAdd(p + 3, (double)(b * tl));
            atomicAdd(p + 4, (double)(b * cl));
        }
    }
    float rep = q * repn;
    if (!valid) { att = 0.f; rep = 0.f; }

    __shared__ float s0[4], s1[4];
    float a = wave_sum(att), r = wave_sum(rep);
    int lane = threadIdx.x & 63, w = threadIdx.x >> 6;
    if (lane == 0) { s0[w] = a; s1[w] = r; }
    __syncthreads();
    if (threadIdx.x == 0) {
        atomicAdd(&ws->acc[0], (double)(s0[0] + s0[1] + s0[2] + s0[3]));
        atomicAdd(&ws->acc[1], (double)(s1[0] + s1[1] + s1[2] + s1[3]));
    }
}

// ---------------- pass 4: merge payload copies + finalize scalar loss ----------------
__global__ __launch_bounds__(256) void k_final(const WS* __restrict__ ws,
                                               float* __restrict__ out, int n) {
    int k = threadIdx.x;
    double pw = 0.0, c1 = 0.0, c2 = 0.0, c3 = 0.0, c4 = 0.0;
    #pragma unroll 4
    for (int c = 0; c < NCOPY; ++c) {
        const double* p = ws->pay[k][c];   // contiguous per-thread -> coalesced-ish
        pw += p[0]; c1 += p[1]; c2 += p[2]; c3 += p[3]; c4 += p[4];
    }
    double ps = ((c1 + c2) + (c3 + c4)) / (pw + 1e-6);  // zero for empty k

    ps = wave_sum_d(ps);
    __shared__ double sd[4];
    int lane = threadIdx.x & 63, w = threadIdx.x >> 6;
    if (lane == 0) sd[w] = ps;
    __syncthreads();
    if (threadIdx.x == 0) {
        double ptotal = sd[0] + sd[1] + sd[2] + sd[3];
        double att = ws->acc[0] / (double)n;
        double rep = ws->acc[1] / (double)n;
        double noise = ws->acc[2] / (ws->acc[3] + 1e-6);
        double nobj = ws->acc[5];
        double minb = ws->acc[4] / (nobj + 1e-6);
        double pay = ptotal / (nobj + 1e-6);
        out[0] = (float)(att + rep + minb + noise + pay);
    }
}

extern "C" void kernel_launch(void* const* d_in, const int* in_sizes, int n_in,
                              void* d_out, int out_size, void* d_ws, size_t ws_size,
                              hipStream_t stream) {
    const float*  pred_beta = (const float*)d_in[0];
    const float2* ccoords   = (const float2*)d_in[1];
    const float*  energy    = (const float*)d_in[2];
    const float2* pos       = (const float2*)d_in[3];
    const float*  ptime     = (const float*)d_in[4];
    const float*  pid       = (const float*)d_in[5];
    const int*    tix       = (const int*)d_in[6];
    const float*  teng      = (const float*)d_in[7];
    const float2* tpos      = (const float2*)d_in[8];
    const float*  ttime     = (const float*)d_in[9];
    int n = in_sizes[0];
    WS* ws = (WS*)d_ws;

    hipMemsetAsync(d_ws, 0, sizeof(WS), stream);

    int blocks = (n + 255) / 256;
    k_pass1<<<blocks, 256, 0, stream>>>(pred_beta, tix, n, ws);
    k_gather<<<1, 256, 0, stream>>>(pred_beta, ccoords, ws);
    k_main<<<blocks, 256, 0, stream>>>(pred_beta, ccoords, energy, pos, ptime, pid,
                                       tix, teng, tpos, ttime, n, ws);
    k_final<<<1, 256, 0, stream>>>(ws, (float*)d_out, n);
}

// Round 4
// 89.834 us; speedup vs baseline: 1.1782x; 1.1782x over previous
//
#include <hip/hip_runtime.h>

#define KOBJ 256
#define NCOPY 32
#define KCHUNK 64            // k's per block (grid.y = KOBJ/KCHUNK = 4)
#define PPT 4                // points per thread
#define EPSF 1e-6f
#define QMIN 0.5f

struct WS {
    float4 adata[KOBJ];                    // x_alpha, y_alpha, q_alpha (0 if empty), beta_alpha
    unsigned long long key[NCOPY][KOBJ];   // privatized argmax keys
    double pay[KOBJ][NCOPY][5];            // privatized payload sums: pw + 4 components
    double acc[8];                         // 0:att 1:rep 2:noise_b 3:noise_cnt 4:minb 5:nobj 6:paysum
};

__device__ inline float clipb(float b) {
    return fminf(fmaxf(b, 1e-4f), 1.0f - 1e-4f);
}

__device__ inline float wave_sum(float v) {
    #pragma unroll
    for (int o = 32; o > 0; o >>= 1) v += __shfl_down(v, o, 64);
    return v;
}

// ---------------- pass 1: per-object argmax of beta (privatized) + noise sums ----------------
__global__ __launch_bounds__(256) void k_pass1(const float* __restrict__ beta_in,
                                               const int* __restrict__ tidx,
                                               int n, WS* __restrict__ ws) {
    int i = blockIdx.x * 256 + threadIdx.x;
    int c = blockIdx.x & (NCOPY - 1);
    float nb = 0.f, ncnt = 0.f;
    if (i < n) {
        float b = clipb(beta_in[i]);
        int t = tidx[i];
        if (t >= 0) {
            unsigned int bits = __float_as_uint(b);  // b>0 -> bits monotone in b
            unsigned long long kv =
                ((unsigned long long)bits << 32) | (unsigned long long)(0xFFFFFFFFu - (unsigned int)i);
            atomicMax(&ws->key[c][t], kv);
        } else {
            nb = b; ncnt = 1.f;   // noise point
        }
    }
    __shared__ float s0[4], s1[4];
    float a = wave_sum(nb), cc = wave_sum(ncnt);
    int lane = threadIdx.x & 63, w = threadIdx.x >> 6;
    if (lane == 0) { s0[w] = a; s1[w] = cc; }
    __syncthreads();
    if (threadIdx.x == 0) {
        float A = s0[0] + s0[1] + s0[2] + s0[3];
        float C = s1[0] + s1[1] + s1[2] + s1[3];
        if (C != 0.f) {
            atomicAdd(&ws->acc[2], (double)A);
            atomicAdd(&ws->acc[3], (double)C);
        }
    }
}

// ---------------- pass 2: merge keys, gather alpha data per object ----------------
__global__ __launch_bounds__(256) void k_gather(const float* __restrict__ beta_in,
                                                const float2* __restrict__ ccoords,
                                                WS* __restrict__ ws) {
    int k = threadIdx.x;
    unsigned long long kv = 0ull;
    #pragma unroll 8
    for (int c = 0; c < NCOPY; ++c) {
        unsigned long long v = ws->key[c][k];
        kv = v > kv ? v : kv;
    }
    float minb = 0.f, nobj = 0.f;
    if (kv != 0ull) {
        unsigned int idx = 0xFFFFFFFFu - (unsigned int)(kv & 0xFFFFFFFFull);
        float b = clipb(beta_in[idx]);
        float at = atanhf(b);
        float qa = at * at + QMIN;
        float2 xy = ccoords[idx];
        ws->adata[k] = make_float4(xy.x, xy.y, qa, b);
        minb = 1.f - b; nobj = 1.f;
    } else {
        ws->adata[k] = make_float4(0.f, 0.f, 0.f, 0.f);
    }
    __shared__ float s0[4], s1[4];
    float a = wave_sum(minb), c = wave_sum(nobj);
    int lane = threadIdx.x & 63, w = threadIdx.x >> 6;
    if (lane == 0) { s0[w] = a; s1[w] = c; }
    __syncthreads();
    if (threadIdx.x == 0) {
        ws->acc[4] = (double)(s0[0] + s0[1] + s0[2] + s0[3]);
        ws->acc[5] = (double)(s1[0] + s1[1] + s1[2] + s1[3]);
    }
}

__device__ inline float repterm(float4 a, float cx, float cy) {
    float dx = cx - a.x, dy = cy - a.y;
    float d2e = fmaf(dx, dx, fmaf(dy, dy, EPSF));
    float s = __builtin_amdgcn_sqrtf(d2e);
    return a.z * fmaxf(1.f - s, 0.f);
}

// ---------------- pass 3: main pass, register-tiled P points x K-chunk ----------------
// grid = (ceil(n/(256*PPT)), KOBJ/KCHUNK)
__global__ __launch_bounds__(256) void k_main(const float* __restrict__ beta_in,
                                              const float2* __restrict__ ccoords,
                                              const float* __restrict__ energy,
                                              const float2* __restrict__ pos,
                                              const float* __restrict__ ptime,
                                              const float* __restrict__ pid,
                                              const int* __restrict__ tidx,
                                              const float* __restrict__ tenergy,
                                              const float2* __restrict__ tpos,
                                              const float* __restrict__ ttime,
                                              int n, WS* __restrict__ ws) {
    __shared__ float4 ad[KCHUNK];
    const int kbase = blockIdx.y * KCHUNK;
    if (threadIdx.x < KCHUNK) ad[threadIdx.x] = ws->adata[kbase + threadIdx.x];
    __syncthreads();

    const int base = blockIdx.x * (256 * PPT) + threadIdx.x;
    const int cpy = blockIdx.x & (NCOPY - 1);

    float cx[PPT], cy[PPT], q[PPT], bb[PPT];
    int tt[PPT];
    #pragma unroll
    for (int p = 0; p < PPT; ++p) {
        int i = base + p * 256;
        bool v = i < n;
        int ii = v ? i : 0;
        float b = clipb(beta_in[ii]);
        float at = atanhf(b);
        float2 xy = ccoords[ii];
        cx[p] = xy.x; cy[p] = xy.y;
        q[p] = v ? (at * at + QMIN) : 0.f;   // q=0 kills rep/att for tail lanes
        bb[p] = b;
        tt[p] = v ? tidx[ii] : -1;
    }

    float racc[PPT];
    #pragma unroll
    for (int p = 0; p < PPT; ++p) racc[p] = 0.f;

    #pragma unroll 4
    for (int k = 0; k < KCHUNK; ++k) {
        float4 a = ad[k];                    // uniform address -> broadcast, no conflicts
        #pragma unroll
        for (int p = 0; p < PPT; ++p)
            racc[p] += repterm(a, cx[p], cy[p]);
    }

    float attv = 0.f, repv = 0.f;
    #pragma unroll
    for (int p = 0; p < PPT; ++p) {
        int tl = tt[p] - kbase;
        if (tl >= 0 && tl < KCHUNK) {        // this block's chunk owns the point's object
            float4 a = ad[tl];
            float dx = cx[p] - a.x, dy = cy[p] - a.y;
            float d2 = fmaf(dx, dx, dy * dy);          // att uses d2 WITHOUT eps
            racc[p] -= repterm(a, cx[p], cy[p]);       // exclude own k from repulsion
            attv += q[p] * a.z * d2;

            if (bb[p] > 0.1f * a.w) {                  // payload weight condition
                int i = base + p * 256;
                float te = tenergy[i];
                float ste = __builtin_amdgcn_sqrtf(te + 0.001f);
                float l = fabsf(te - energy[i]) / (ste + 1.0f);
                float d = ste * 2.0f;
                float el = (l < d) ? l * l : fmaf(2.f * d, l - d, d * d);
                float2 pp = pos[i], tp = tpos[i];
                float px = pp.x - tp.x, py = pp.y - tp.y;
                float pl = fmaf(px, px, py * py) * 0.01f;
                float td = ttime[i] * 1e9f - ptime[i];
                float tl2 = td * td;
                float s = 0.f;
                #pragma unroll
                for (int cc = 0; cc < 6; ++cc) { float v = pid[6 * i + cc]; s = fmaf(v, v, s); }
                float cl = 1e-8f * (s * (1.f / 6.f));
                double* pp5 = ws->pay[tt[p]][cpy];
                float b = bb[p];
                atomicAdd(pp5 + 0, (double)b);
                atomicAdd(pp5 + 1, (double)(b * el));
                atomicAdd(pp5 + 2, (double)(b * pl));
                atomicAdd(pp5 + 3, (double)(b * tl2));
                atomicAdd(pp5 + 4, (double)(b * cl));
            }
        }
        repv += q[p] * racc[p];
    }

    __shared__ float s0[4], s1[4];
    float a = wave_sum(attv), r = wave_sum(repv);
    int lane = threadIdx.x & 63, w = threadIdx.x >> 6;
    if (lane == 0) { s0[w] = a; s1[w] = r; }
    __syncthreads();
    if (threadIdx.x == 0) {
        float A = s0[0] + s0[1] + s0[2] + s0[3];
        float R = s1[0] + s1[1] + s1[2] + s1[3];
        if (A != 0.f) atomicAdd(&ws->acc[0], (double)A);
        if (R != 0.f) atomicAdd(&ws->acc[1], (double)R);
    }
}

// ---------------- pass 4: parallel payload merge (32 lanes per object) ----------------
// grid = 32 blocks x 256 threads; each 32-lane group handles one k
__global__ __launch_bounds__(256) void k_merge(WS* __restrict__ ws) {
    int c = threadIdx.x & 31;
    int k = blockIdx.x * 8 + (threadIdx.x >> 5);
    const double* p = ws->pay[k][c];
    double pw = p[0];
    double s = (p[1] + p[2]) + (p[3] + p[4]);
    #pragma unroll
    for (int o = 16; o > 0; o >>= 1) {
        pw += __shfl_down(pw, o, 32);
        s  += __shfl_down(s, o, 32);
    }
    if (c == 0 && s != 0.0) {
        atomicAdd(&ws->acc[6], s / (pw + 1e-6));
    }
}

// ---------------- pass 5: finalize scalar loss ----------------
__global__ void k_final(const WS* __restrict__ ws, float* __restrict__ out, int n) {
    if (threadIdx.x == 0) {
        double att = ws->acc[0] / (double)n;
        double rep = ws->acc[1] / (double)n;
        double noise = ws->acc[2] / (ws->acc[3] + 1e-6);
        double nobj = ws->acc[5];
        double minb = ws->acc[4] / (nobj + 1e-6);
        double pay = ws->acc[6] / (nobj + 1e-6);
        out[0] = (float)(att + rep + minb + noise + pay);
    }
}

extern "C" void kernel_launch(void* const* d_in, const int* in_sizes, int n_in,
                              void* d_out, int out_size, void* d_ws, size_t ws_size,
                              hipStream_t stream) {
    const float*  pred_beta = (const float*)d_in[0];
    const float2* ccoords   = (const float2*)d_in[1];
    const float*  energy    = (const float*)d_in[2];
    const float2* pos       = (const float2*)d_in[3];
    const float*  ptime     = (const float*)d_in[4];
    const float*  pid       = (const float*)d_in[5];
    const int*    tix       = (const int*)d_in[6];
    const float*  teng      = (const float*)d_in[7];
    const float2* tpos      = (const float2*)d_in[8];
    const float*  ttime     = (const float*)d_in[9];
    int n = in_sizes[0];
    WS* ws = (WS*)d_ws;

    hipMemsetAsync(d_ws, 0, sizeof(WS), stream);

    int blocks1 = (n + 255) / 256;
    k_pass1<<<blocks1, 256, 0, stream>>>(pred_beta, tix, n, ws);
    k_gather<<<1, 256, 0, stream>>>(pred_beta, ccoords, ws);

    dim3 grid((n + 256 * PPT - 1) / (256 * PPT), KOBJ / KCHUNK);
    k_main<<<grid, 256, 0, stream>>>(pred_beta, ccoords, energy, pos, ptime, pid,
                                     tix, teng, tpos, ttime, n, ws);
    k_merge<<<32, 256, 0, stream>>>(ws);
    k_final<<<1, 64, 0, stream>>>(ws, (float*)d_out, n);
}